// Round 5
// baseline (264.493 us; speedup 1.0000x reference)
//
#include <hip/hip_runtime.h>

#define HH 64
#define WW 64

typedef _Float16 f16;
typedef f16 f16x8 __attribute__((ext_vector_type(8)));
typedef f16 f16x4 __attribute__((ext_vector_type(4)));
typedef f16 f16x2 __attribute__((ext_vector_type(2)));
typedef float f32x4 __attribute__((ext_vector_type(4)));

// ws: ws[0..63] = fp32 logit bias; then f16 region (offsets in halves):
#define M1_H 0         // [c][r*4+s][lane][j] : 49152
#define BU_H 49152     // [c][r*4+s][lane][j] : 49152
#define BF_H 98304     // [g][r][lane][j]     : 12288
#define BC_H 110592    // [c2][s][lane][j]    : 4096
#define VT_H 114688    // [pixel][ch=n*8+slot]: 8388608  (slot: d=2*(slot&3)+(slot>>2))
#define PREP_N (64 + 114688)

union U2 { f16x2 v; int i; };

__global__ __launch_bounds__(256) void prep_kernel(
    const float* __restrict__ attw, const float* __restrict__ ctw,
    const float* __restrict__ ctb, const float* __restrict__ few,
    const float* __restrict__ caw, float* __restrict__ ws) {
  int i = blockIdx.x * 256 + threadIdx.x;
  if (i >= PREP_N) return;
  f16* hb = (f16*)(ws + 64);
  if (i < 64) {
    int s = i >> 4, l15 = i & 15;
    int o = 2 * s + (l15 >> 3), n = l15 & 7;
    float acc = 0.f;
    for (int c = 0; c < 8; ++c)
      for (int d = 0; d < 8; ++d)
        acc += ctb[c * 64 + d * 8 + n] * attw[d * 512 + c * 64 + n * 8 + o];
    ws[i] = acc;
    return;
  }
  int z = i - 64;
  if (z < BU_H) {
    // M1[kappa=(c, t=r*4+q, dd=j)][col=(o=2s+h, n)] = sum_d ctw*attw
    int j = z & 7, lane = (z >> 3) & 63, rest = z >> 9;
    int rs = rest % 12, c = rest / 12;
    int r = rs >> 2, s = rs & 3;
    int q = lane >> 4, l15 = lane & 15;
    int t = r * 4 + q;
    int o = 2 * s + (l15 >> 3), n = l15 & 7;
    float acc = 0.f;
    if (t < 9)
      for (int d = 0; d < 8; ++d)
        acc += ctw[(t * 8 + j) * 512 + c * 64 + d * 8 + n] *
               attw[d * 512 + c * 64 + n * 8 + o];
    hb[M1_H + z] = (f16)acc;
  } else if (z < BF_H) {
    // Bu[kappa=(c,t,dd=j)][col=(d=2s+h, n)] = ctw
    int z2 = z - BU_H;
    int j = z2 & 7, lane = (z2 >> 3) & 63, rest = z2 >> 9;
    int rs = rest % 12, c = rest / 12;
    int r = rs >> 2, s = rs & 3;
    int q = lane >> 4, l15 = lane & 15;
    int t = r * 4 + q;
    int d = 2 * s + (l15 >> 3), n = l15 & 7;
    float v = (t < 9) ? ctw[(t * 8 + j) * 512 + c * 64 + d * 8 + n] : 0.f;
    hb[z] = (f16)v;
  } else if (z < BC_H) {
    // Bf[g][r][lane][j]: kappa=(t=r*4+q, ch=g*8+j); col n=2*(g>>1)+(l15>>3), jcol=l15&7
    int z2 = z - BF_H;
    int j = z2 & 7, lane = (z2 >> 3) & 63, rest = z2 >> 9;
    int r = rest % 3, g = rest / 3;
    int q = lane >> 4, l15 = lane & 15;
    int t = r * 4 + q;
    int d = 2 * (j & 3) + (j >> 2);
    float v = 0.f;
    if (t < 9 && ((l15 >> 3) == (g & 1)))
      v = few[(t * 8 + d) * 64 + g * 8 + (l15 & 7)];
    hb[z] = (f16)v;
  } else if (z < VT_H) {
    // Bc[c2][s][lane][j]: kappa n_k=c2*4+q, j1=j; col n=2s+(l15>>3), j2=l15&7
    int z2 = z - BC_H;
    int j = z2 & 7, lane = (z2 >> 3) & 63, rest = z2 >> 9;
    int s = rest & 3, c2 = rest >> 2;
    int q = lane >> 4, l15 = lane & 15;
    int nk = c2 * 4 + q;
    int nc = 2 * s + (l15 >> 3);
    float v = (nk == nc) ? caw[j * 64 + nc * 8 + (l15 & 7)] : 0.f;
    hb[z] = (f16)v;
  }
}

// Stage 1: logits GEMM -> register softmax+exchange -> u GEMM + att fold -> vt
// 256 thr = 4 waves; tile 16(y) x 8(x); wave w owns M-tiles {2w, 2w+1}.
__global__ __launch_bounds__(256, 4) void caps_stage1(
    const float* __restrict__ in, const float* __restrict__ ws,
    const float* __restrict__ ctb, f16* __restrict__ vt) {
  __shared__ f16 xt[181 * 72];  // 26 KB; reused as vtmp[128*72] in epilogue
  int bid = blockIdx.x;
  int b = bid >> 5, t5 = bid & 31;
  int ty = t5 >> 3, tx = t5 & 7;
  int tid = threadIdx.x;

  // fill halo tile (fp32 -> f16, transpose to ch=c*8+dd), hp=180 = zero row
  for (int i = tid; i < 181 * 8; i += 256) {
    int c = i & 7, hp = i >> 3;
    float xs[8] = {0.f, 0.f, 0.f, 0.f, 0.f, 0.f, 0.f, 0.f};
    if (hp < 180) {
      int hy = hp / 10, hx = hp - hy * 10;
      int gy = ty * 16 + hy - 1, gx = tx * 8 + hx - 1;
      if (gy >= 0 && gy < HH && gx >= 0 && gx < WW) {
        const float* src = in + (((b * HH + gy) * WW + gx) * 64 + c);
#pragma unroll
        for (int d = 0; d < 8; ++d) xs[d] = src[d * 8];
      }
    }
    f16x8 pk;
#pragma unroll
    for (int d = 0; d < 8; ++d) pk[d] = (f16)xs[d];
    *(f16x8*)&xt[hp * 72 + c * 8] = pk;
  }
  __syncthreads();

  int w = __builtin_amdgcn_readfirstlane(tid >> 6);
  int lane = tid & 63;
  int q = lane >> 4, l15 = lane & 15;
  int h = l15 >> 3, n = l15 & 7;

  int hpt[2][3];
#pragma unroll
  for (int i2 = 0; i2 < 2; ++i2) {
    int pyA = (2 * w + i2) * 2 + h;
    int pxA = l15 & 7;
#pragma unroll
    for (int r = 0; r < 3; ++r) {
      int t = r * 4 + q;
      int hp = 180;
      if (t < 9) {
        int ky = t / 3, kx = t - ky * 3;
        hp = (pyA + ky) * 10 + pxA + kx;
      }
      hpt[i2][r] = hp * 72;
    }
  }

  const f16x8* m1v = (const f16x8*)((const f16*)(ws + 64) + M1_H);
  const f16x8* buv = (const f16x8*)((const f16*)(ws + 64) + BU_H);
  const float* lb = ws;

  // ---- pass 1: logits ----
  f32x4 L[2][4];
#pragma unroll
  for (int s = 0; s < 4; ++s) {
    float v0 = lb[s * 16 + l15];
    L[0][s] = (f32x4){v0, v0, v0, v0};
    L[1][s] = (f32x4){v0, v0, v0, v0};
  }
#pragma unroll 1
  for (int c = 0; c < 8; ++c) {
    f16x8 a2[2][3];
#pragma unroll
    for (int i2 = 0; i2 < 2; ++i2)
#pragma unroll
      for (int r = 0; r < 3; ++r)
        a2[i2][r] = *(const f16x8*)&xt[hpt[i2][r] + c * 8];
#pragma unroll
    for (int s = 0; s < 4; ++s) {
      f16x8 bm[3];
#pragma unroll
      for (int r = 0; r < 3; ++r) bm[r] = m1v[(c * 12 + r * 4 + s) * 64 + lane];
#pragma unroll
      for (int i2 = 0; i2 < 2; ++i2)
#pragma unroll
        for (int r = 0; r < 3; ++r)
          L[i2][s] = __builtin_amdgcn_mfma_f32_16x16x32_f16(
              a2[i2][r], bm[r], L[i2][s], 0, 0, 0);
    }
  }

  // ---- softmax over o: 4 in-lane + 4 via lane^8; att kept in registers ----
  f16x2 P[2][4][4];  // [i2][r][spair] = (att[2sp], att[2sp+1]) for own row, col n
#pragma unroll
  for (int i2 = 0; i2 < 2; ++i2)
#pragma unroll
    for (int r = 0; r < 4; ++r) {
      float v0 = L[i2][0][r], v1 = L[i2][1][r], v2 = L[i2][2][r], v3 = L[i2][3][r];
      float pm = fmaxf(fmaxf(v0, v1), fmaxf(v2, v3));
      float m = fmaxf(pm, __shfl_xor(pm, 8));
      float e0 = __expf(v0 - m), e1 = __expf(v1 - m);
      float e2 = __expf(v2 - m), e3 = __expf(v3 - m);
      float ps = e0 + e1 + e2 + e3;
      float inv = 1.f / (ps + __shfl_xor(ps, 8));
      f16 o0 = (f16)(e0 * inv), o1 = (f16)(e1 * inv);
      f16 o2 = (f16)(e2 * inv), o3 = (f16)(e3 * inv);
      U2 p01, p23, r01, r23;
      p01.v = (f16x2){o0, o1};
      p23.v = (f16x2){o2, o3};
      r01.i = __shfl_xor(p01.i, 8);
      r23.i = __shfl_xor(p23.i, 8);
      // own holds o=2s+h, partner holds o=2s+1-h
      P[i2][r][0] = h ? (f16x2){r01.v[0], o0} : (f16x2){o0, r01.v[0]};
      P[i2][r][1] = h ? (f16x2){r01.v[1], o1} : (f16x2){o1, r01.v[1]};
      P[i2][r][2] = h ? (f16x2){r23.v[0], o2} : (f16x2){o2, r23.v[0]};
      P[i2][r][3] = h ? (f16x2){r23.v[1], o3} : (f16x2){o3, r23.v[1]};
    }

  // ---- pass 2: u GEMM per c + in-register attention fold ----
  f32x4 V[2][4];
#pragma unroll
  for (int s = 0; s < 4; ++s) {
    V[0][s] = (f32x4){0.f, 0.f, 0.f, 0.f};
    V[1][s] = (f32x4){0.f, 0.f, 0.f, 0.f};
  }
#pragma unroll
  for (int c = 0; c < 8; ++c) {
    f16x8 a2[2][3];
#pragma unroll
    for (int i2 = 0; i2 < 2; ++i2)
#pragma unroll
      for (int r = 0; r < 3; ++r)
        a2[i2][r] = *(const f16x8*)&xt[hpt[i2][r] + c * 8];
    float attf[2][4];
#pragma unroll
    for (int i2 = 0; i2 < 2; ++i2)
#pragma unroll
      for (int r = 0; r < 4; ++r)
        attf[i2][r] = (float)P[i2][r][c >> 1][c & 1];
#pragma unroll
    for (int s = 0; s < 4; ++s) {
      f16x8 bu[3];
#pragma unroll
      for (int r = 0; r < 3; ++r) bu[r] = buv[(c * 12 + r * 4 + s) * 64 + lane];
      float bv = ctb[c * 64 + s * 16 + l15];
#pragma unroll
      for (int i2 = 0; i2 < 2; ++i2) {
        f32x4 U = (f32x4){bv, bv, bv, bv};
#pragma unroll
        for (int r = 0; r < 3; ++r)
          U = __builtin_amdgcn_mfma_f32_16x16x32_f16(a2[i2][r], bu[r], U, 0, 0, 0);
#pragma unroll
        for (int r = 0; r < 4; ++r) V[i2][s][r] += U[r] * attf[i2][r];
      }
    }
  }

  // ---- epilogue: transpose V through LDS, coalesced f16 b128 stores ----
  __syncthreads();
  f16* vtmp = xt;
#pragma unroll
  for (int i2 = 0; i2 < 2; ++i2)
#pragma unroll
    for (int r = 0; r < 4; ++r) {
      int p = (2 * w + i2) * 16 + q * 4 + r;
      f16x4 st;
#pragma unroll
      for (int s = 0; s < 4; ++s) st[s] = (f16)V[i2][s][r];  // slot=h*4+s, d=2s+h
      *(f16x4*)&vtmp[p * 72 + n * 8 + h * 4] = st;
    }
  __syncthreads();
  for (int idx = tid; idx < 1024; idx += 256) {
    int p = idx >> 3, q2 = idx & 7;
    float4 val = *(float4*)&vtmp[p * 72 + q2 * 8];
    int gy = ty * 16 + (p >> 3), gx = tx * 8 + (p & 7);
    ((float4*)(vt + ((b * HH + gy) * WW + gx) * 64))[q2] = val;
  }
}

// Stage 2: FeaExt GEMM (block-diag, 1 s-frag per chunk) + ReLU + CapsAct GEMM -> out
__global__ __launch_bounds__(256, 4) void caps_stage2(
    const f16* __restrict__ vt, const float* __restrict__ ws,
    const float* __restrict__ fb, const float* __restrict__ cab,
    float* __restrict__ out) {
  __shared__ float smemf[8704];  // 34816 B: vtile(26064) / h1t(18432) / outbuf(34816) aliased
  f16* vtile = (f16*)smemf;
  int bid = blockIdx.x;
  int b = bid >> 5, t5 = bid & 31;
  int ty = t5 >> 3, tx = t5 & 7;
  int tid = threadIdx.x;

  for (int i = tid; i < 181 * 8; i += 256) {
    int q2 = i & 7, hp = i >> 3;
    float4 val = make_float4(0.f, 0.f, 0.f, 0.f);
    if (hp < 180) {
      int hy = hp / 10, hx = hp - hy * 10;
      int gy = ty * 16 + hy - 1, gx = tx * 8 + hx - 1;
      if (gy >= 0 && gy < HH && gx >= 0 && gx < WW)
        val = ((const float4*)(vt + ((b * HH + gy) * WW + gx) * 64))[q2];
    }
    *(float4*)&vtile[hp * 72 + q2 * 8] = val;
  }
  __syncthreads();

  int w = __builtin_amdgcn_readfirstlane(tid >> 6);
  int lane = tid & 63;
  int q = lane >> 4, l15 = lane & 15;
  int h = l15 >> 3, j7 = l15 & 7;

  int hpt[2][3];
#pragma unroll
  for (int i2 = 0; i2 < 2; ++i2) {
    int pyA = (2 * w + i2) * 2 + h;
#pragma unroll
    for (int r = 0; r < 3; ++r) {
      int t = r * 4 + q;
      int hp = 180;
      if (t < 9) {
        int ky = t / 3, kx = t - ky * 3;
        hp = (pyA + ky) * 10 + j7 + kx;
      }
      hpt[i2][r] = hp * 72;
    }
  }

  const f16x8* bfv = (const f16x8*)((const f16*)(ws + 64) + BF_H);
  const f16x8* bcv = (const f16x8*)((const f16*)(ws + 64) + BC_H);

  // FeaExt: col (n=2s+h, j=j7); chunk g feeds only s=g>>1
  f32x4 L[2][4];
#pragma unroll
  for (int s = 0; s < 4; ++s) {
    float bvv = fb[(2 * s + h) * 8 + j7];
    L[0][s] = (f32x4){bvv, bvv, bvv, bvv};
    L[1][s] = (f32x4){bvv, bvv, bvv, bvv};
  }
#pragma unroll
  for (int g = 0; g < 8; ++g) {
    int sg = g >> 1;
#pragma unroll
    for (int r = 0; r < 3; ++r) {
      f16x8 bf = bfv[(g * 3 + r) * 64 + lane];
#pragma unroll
      for (int i2 = 0; i2 < 2; ++i2) {
        f16x8 a = *(const f16x8*)&vtile[hpt[i2][r] + g * 8];
        L[i2][sg] = __builtin_amdgcn_mfma_f32_16x16x32_f16(a, bf, L[i2][sg], 0, 0, 0);
      }
    }
  }
#pragma unroll
  for (int i2 = 0; i2 < 2; ++i2)
#pragma unroll
    for (int s = 0; s < 4; ++s)
#pragma unroll
      for (int r = 0; r < 4; ++r) L[i2][s][r] = fmaxf(L[i2][s][r], 0.f);

  __syncthreads();  // vtile reads done; alias h1t
  f16* h1t = (f16*)smemf;  // [128][72], ch2 = n*8 + j1
#pragma unroll
  for (int i2 = 0; i2 < 2; ++i2)
#pragma unroll
    for (int s = 0; s < 4; ++s)
#pragma unroll
      for (int r = 0; r < 4; ++r)
        h1t[((2 * w + i2) * 16 + q * 4 + r) * 72 + (2 * s + h) * 8 + j7] =
            (f16)L[i2][s][r];
  __syncthreads();

  // CapsAct: K=64 over (j1, n) block-diag
  f32x4 H[2][4];
#pragma unroll
  for (int s = 0; s < 4; ++s) {
    float bvv = cab[(2 * s + h) * 8 + j7];
    H[0][s] = (f32x4){bvv, bvv, bvv, bvv};
    H[1][s] = (f32x4){bvv, bvv, bvv, bvv};
  }
#pragma unroll
  for (int c2 = 0; c2 < 2; ++c2) {
    f16x8 a2[2];
#pragma unroll
    for (int i2 = 0; i2 < 2; ++i2)
      a2[i2] = *(const f16x8*)&h1t[((2 * w + i2) * 16 + l15) * 72 + c2 * 32 + q * 8];
#pragma unroll
    for (int s = 0; s < 4; ++s) {
      f16x8 bc = bcv[(c2 * 4 + s) * 64 + lane];
#pragma unroll
      for (int i2 = 0; i2 < 2; ++i2)
        H[i2][s] = __builtin_amdgcn_mfma_f32_16x16x32_f16(a2[i2], bc, H[i2][s], 0, 0, 0);
    }
  }

  __syncthreads();  // h1t reads done; alias outbuf
  float* outbuf = smemf;  // [128][68], ch = j2*8 + n
#pragma unroll
  for (int i2 = 0; i2 < 2; ++i2)
#pragma unroll
    for (int s = 0; s < 4; ++s)
#pragma unroll
      for (int r = 0; r < 4; ++r)
        outbuf[((2 * w + i2) * 16 + q * 4 + r) * 68 + j7 * 8 + 2 * s + h] =
            H[i2][s][r];
  __syncthreads();

  for (int idx = tid; idx < 2048; idx += 256) {
    int p = idx >> 4, q4 = idx & 15;
    float4 val = *(float4*)&outbuf[p * 68 + q4 * 4];
    int gy = ty * 16 + (p >> 3), gx = tx * 8 + (p & 7);
    *(float4*)(out + ((b * HH + gy) * WW + gx) * 64 + q4 * 4) = val;
  }
}

extern "C" void kernel_launch(void* const* d_in, const int* in_sizes, int n_in,
                              void* d_out, int out_size, void* d_ws, size_t ws_size,
                              hipStream_t stream) {
  const float* inputs = (const float*)d_in[0];
  const float* attw   = (const float*)d_in[1];
  const float* ctw    = (const float*)d_in[2];
  const float* ctb    = (const float*)d_in[3];
  const float* few    = (const float*)d_in[4];
  const float* fb     = (const float*)d_in[5];
  const float* caw    = (const float*)d_in[6];
  const float* cab    = (const float*)d_in[7];
  float* out = (float*)d_out;
  float* ws  = (float*)d_ws;
  f16* vt = (f16*)(ws + 64) + VT_H;

  prep_kernel<<<(PREP_N + 255) / 256, 256, 0, stream>>>(attw, ctw, ctb, few, caw, ws);
  caps_stage1<<<32 * 32, 256, 0, stream>>>(inputs, ws, ctb, vt);
  caps_stage2<<<32 * 32, 256, 0, stream>>>(vt, ws, fb, cab, out);
}

// Round 6
// 149.882 us; speedup vs baseline: 1.7647x; 1.7647x over previous
//
#include <hip/hip_runtime.h>

#define HH 64
#define WW 64

typedef _Float16 f16;
typedef f16 f16x8 __attribute__((ext_vector_type(8)));
typedef f16 f16x4 __attribute__((ext_vector_type(4)));
typedef float f32x4 __attribute__((ext_vector_type(4)));

// ws: ws[0..63] = fp32 logit bias; then f16 region (offsets in halves):
#define M1_H 0         // [c][r*4+s][lane][j] : 49152
#define BU_H 49152     // [c][r*4+s][lane][j] : 49152
#define BF_H 98304     // [g][r][lane][j]     : 12288
#define BC_H 110592    // [c2][s][lane][j]    : 4096
#define VT_H 114688    // [pixel][ch=n*8+slot]: 8388608  (slot: d=2*(slot&3)+(slot>>2))
#define PREP_N (64 + 114688)

__global__ __launch_bounds__(256) void prep_kernel(
    const float* __restrict__ attw, const float* __restrict__ ctw,
    const float* __restrict__ ctb, const float* __restrict__ few,
    const float* __restrict__ caw, float* __restrict__ ws) {
  int i = blockIdx.x * 256 + threadIdx.x;
  if (i >= PREP_N) return;
  f16* hb = (f16*)(ws + 64);
  if (i < 64) {
    int s = i >> 4, l15 = i & 15;
    int o = 2 * s + (l15 >> 3), n = l15 & 7;
    float acc = 0.f;
    for (int c = 0; c < 8; ++c)
      for (int d = 0; d < 8; ++d)
        acc += ctb[c * 64 + d * 8 + n] * attw[d * 512 + c * 64 + n * 8 + o];
    ws[i] = acc;
    return;
  }
  int z = i - 64;
  if (z < BU_H) {
    // M1[kappa=(c, t=r*4+q, dd=j)][col=(o=2s+h, n)] = sum_d ctw*attw
    int j = z & 7, lane = (z >> 3) & 63, rest = z >> 9;
    int rs = rest % 12, c = rest / 12;
    int r = rs >> 2, s = rs & 3;
    int q = lane >> 4, l15 = lane & 15;
    int t = r * 4 + q;
    int o = 2 * s + (l15 >> 3), n = l15 & 7;
    float acc = 0.f;
    if (t < 9)
      for (int d = 0; d < 8; ++d)
        acc += ctw[(t * 8 + j) * 512 + c * 64 + d * 8 + n] *
               attw[d * 512 + c * 64 + n * 8 + o];
    hb[M1_H + z] = (f16)acc;
  } else if (z < BF_H) {
    // Bu[kappa=(c,t,dd=j)][col=(d=2s+h, n)] = ctw
    int z2 = z - BU_H;
    int j = z2 & 7, lane = (z2 >> 3) & 63, rest = z2 >> 9;
    int rs = rest % 12, c = rest / 12;
    int r = rs >> 2, s = rs & 3;
    int q = lane >> 4, l15 = lane & 15;
    int t = r * 4 + q;
    int d = 2 * s + (l15 >> 3), n = l15 & 7;
    float v = (t < 9) ? ctw[(t * 8 + j) * 512 + c * 64 + d * 8 + n] : 0.f;
    hb[z] = (f16)v;
  } else if (z < BC_H) {
    // Bf[g][r][lane][j]: kappa=(t=r*4+q, ch=g*8+j); col n=2*(g>>1)+(l15>>3), jcol=l15&7
    int z2 = z - BF_H;
    int j = z2 & 7, lane = (z2 >> 3) & 63, rest = z2 >> 9;
    int r = rest % 3, g = rest / 3;
    int q = lane >> 4, l15 = lane & 15;
    int t = r * 4 + q;
    int d = 2 * (j & 3) + (j >> 2);
    float v = 0.f;
    if (t < 9 && ((l15 >> 3) == (g & 1)))
      v = few[(t * 8 + d) * 64 + g * 8 + (l15 & 7)];
    hb[z] = (f16)v;
  } else if (z < VT_H) {
    // Bc[c2][s][lane][j]: kappa n_k=c2*4+q, j1=j; col n=2s+(l15>>3), j2=l15&7
    int z2 = z - BC_H;
    int j = z2 & 7, lane = (z2 >> 3) & 63, rest = z2 >> 9;
    int s = rest & 3, c2 = rest >> 2;
    int q = lane >> 4, l15 = lane & 15;
    int nk = c2 * 4 + q;
    int nc = 2 * s + (l15 >> 3);
    float v = (nk == nc) ? caw[j * 64 + nc * 8 + (l15 & 7)] : 0.f;
    hb[z] = (f16)v;
  }
}

// Stage 1 (round-4 proven structure, f16): logits GEMM -> softmax via LDS attb ->
// u GEMM + attention fold -> vt. 256 thr = 4 waves; tile 16x8; wave w: M-tiles {2w,2w+1}.
__global__ __launch_bounds__(256, 2) void caps_stage1(
    const float* __restrict__ in, const float* __restrict__ ws,
    const float* __restrict__ ctb, f16* __restrict__ vt) {
  __shared__ f16 xt[181 * 72];    // 26.1 KB, hp=180 = zero row
  __shared__ f16 attb[128 * 72];  // 18.4 KB; reused as vtmp in epilogue
  int bid = blockIdx.x;
  int b = bid >> 5, t5 = bid & 31;
  int ty = t5 >> 3, tx = t5 & 7;
  int tid = threadIdx.x;

  // fill halo tile (fp32 -> f16, transpose to ch = c*8+dd)
  for (int i = tid; i < 181 * 8; i += 256) {
    int c = i & 7, hp = i >> 3;
    float xs[8] = {0.f, 0.f, 0.f, 0.f, 0.f, 0.f, 0.f, 0.f};
    if (hp < 180) {
      int hy = hp / 10, hx = hp - hy * 10;
      int gy = ty * 16 + hy - 1, gx = tx * 8 + hx - 1;
      if (gy >= 0 && gy < HH && gx >= 0 && gx < WW) {
        const float* src = in + (((b * HH + gy) * WW + gx) * 64 + c);
#pragma unroll
        for (int d = 0; d < 8; ++d) xs[d] = src[d * 8];
      }
    }
    f16x8 pk;
#pragma unroll
    for (int d = 0; d < 8; ++d) pk[d] = (f16)xs[d];
    *(f16x8*)&xt[hp * 72 + c * 8] = pk;
  }
  __syncthreads();

  int w = __builtin_amdgcn_readfirstlane(tid >> 6);
  int lane = tid & 63;
  int q = lane >> 4, l15 = lane & 15;
  int h = l15 >> 3, n = l15 & 7;

  int hpt[2][3];
#pragma unroll
  for (int i2 = 0; i2 < 2; ++i2) {
    int pyA = (2 * w + i2) * 2 + h;
    int pxA = l15 & 7;
#pragma unroll
    for (int r = 0; r < 3; ++r) {
      int t = r * 4 + q;
      int hp = 180;
      if (t < 9) {
        int ky = t / 3, kx = t - ky * 3;
        hp = (pyA + ky) * 10 + pxA + kx;
      }
      hpt[i2][r] = hp * 72;
    }
  }

  const f16x8* m1v = (const f16x8*)((const f16*)(ws + 64) + M1_H);
  const f16x8* buv = (const f16x8*)((const f16*)(ws + 64) + BU_H);
  const float* lb = ws;

  // ---- pass 1: attention logits via MFMA ----
  f32x4 L[2][4];
#pragma unroll
  for (int s = 0; s < 4; ++s) {
    float v0 = lb[s * 16 + l15];
    L[0][s] = (f32x4){v0, v0, v0, v0};
    L[1][s] = (f32x4){v0, v0, v0, v0};
  }
#pragma unroll 1
  for (int c = 0; c < 8; ++c) {
    f16x8 bm[12];
#pragma unroll
    for (int rs = 0; rs < 12; ++rs) bm[rs] = m1v[(c * 12 + rs) * 64 + lane];
    f16x8 a[2][3];
#pragma unroll
    for (int i2 = 0; i2 < 2; ++i2)
#pragma unroll
      for (int r = 0; r < 3; ++r)
        a[i2][r] = *(const f16x8*)&xt[hpt[i2][r] + c * 8];
#pragma unroll
    for (int i2 = 0; i2 < 2; ++i2)
#pragma unroll
      for (int s = 0; s < 4; ++s)
#pragma unroll
        for (int r = 0; r < 3; ++r)
          L[i2][s] = __builtin_amdgcn_mfma_f32_16x16x32_f16(
              a[i2][r], bm[r * 4 + s], L[i2][s], 0, 0, 0);
  }

  // ---- softmax over o (4 in-lane s-frags + lane^8), att -> LDS ----
#pragma unroll
  for (int i2 = 0; i2 < 2; ++i2) {
    int pbase = (2 * w + i2) * 16 + q * 4;
#pragma unroll
    for (int r = 0; r < 4; ++r) {
      float v0 = L[i2][0][r], v1 = L[i2][1][r], v2 = L[i2][2][r], v3 = L[i2][3][r];
      float pm = fmaxf(fmaxf(v0, v1), fmaxf(v2, v3));
      float m = fmaxf(pm, __shfl_xor(pm, 8));
      float e0 = __expf(v0 - m), e1 = __expf(v1 - m);
      float e2 = __expf(v2 - m), e3 = __expf(v3 - m);
      float ps = e0 + e1 + e2 + e3;
      float inv = 1.f / (ps + __shfl_xor(ps, 8));
      int ab = (pbase + r) * 72 + n * 8 + h;  // o = 2s + h
      attb[ab + 0] = (f16)(e0 * inv);
      attb[ab + 2] = (f16)(e1 * inv);
      attb[ab + 4] = (f16)(e2 * inv);
      attb[ab + 6] = (f16)(e3 * inv);
    }
  }
  __syncthreads();

  // ---- pass 2: u GEMM per c + attention fold ----
  f16x8 atp[2][4];
#pragma unroll
  for (int i2 = 0; i2 < 2; ++i2)
#pragma unroll
    for (int r = 0; r < 4; ++r)
      atp[i2][r] = *(const f16x8*)&attb[((2 * w + i2) * 16 + q * 4 + r) * 72 + n * 8];

  f32x4 V[2][4];
#pragma unroll
  for (int s = 0; s < 4; ++s) {
    V[0][s] = (f32x4){0.f, 0.f, 0.f, 0.f};
    V[1][s] = (f32x4){0.f, 0.f, 0.f, 0.f};
  }
#pragma unroll 1
  for (int c = 0; c < 8; ++c) {
    f16x8 bu[12];
#pragma unroll
    for (int rs = 0; rs < 12; ++rs) bu[rs] = buv[(c * 12 + rs) * 64 + lane];
    f16x8 a[2][3];
#pragma unroll
    for (int i2 = 0; i2 < 2; ++i2)
#pragma unroll
      for (int r = 0; r < 3; ++r)
        a[i2][r] = *(const f16x8*)&xt[hpt[i2][r] + c * 8];
    f32x4 U[2][4];
#pragma unroll
    for (int s = 0; s < 4; ++s) {
      float bv = ctb[c * 64 + s * 16 + l15];
      U[0][s] = (f32x4){bv, bv, bv, bv};
      U[1][s] = (f32x4){bv, bv, bv, bv};
    }
#pragma unroll
    for (int i2 = 0; i2 < 2; ++i2)
#pragma unroll
      for (int s = 0; s < 4; ++s)
#pragma unroll
        for (int r = 0; r < 3; ++r)
          U[i2][s] = __builtin_amdgcn_mfma_f32_16x16x32_f16(
              a[i2][r], bu[r * 4 + s], U[i2][s], 0, 0, 0);
#pragma unroll
    for (int i2 = 0; i2 < 2; ++i2)
#pragma unroll
      for (int r = 0; r < 4; ++r) {
        float af = (float)atp[i2][r][c];
#pragma unroll
        for (int s = 0; s < 4; ++s) V[i2][s][r] += U[i2][s][r] * af;
      }
  }

  // ---- epilogue: transpose V through attb, coalesced b128 stores ----
  __syncthreads();
  f16* vtmp = attb;
#pragma unroll
  for (int i2 = 0; i2 < 2; ++i2)
#pragma unroll
    for (int r = 0; r < 4; ++r) {
      int p = (2 * w + i2) * 16 + q * 4 + r;
      f16x4 st;
#pragma unroll
      for (int s = 0; s < 4; ++s) st[s] = (f16)V[i2][s][r];  // slot=h*4+s, d=2s+h
      *(f16x4*)&vtmp[p * 72 + n * 8 + h * 4] = st;
    }
  __syncthreads();
  for (int idx = tid; idx < 1024; idx += 256) {
    int p = idx >> 3, q2 = idx & 7;
    float4 val = *(float4*)&vtmp[p * 72 + q2 * 8];
    int gy = ty * 16 + (p >> 3), gx = tx * 8 + (p & 7);
    ((float4*)(vt + ((b * HH + gy) * WW + gx) * 64))[q2] = val;
  }
}

// Stage 2: FeaExt GEMM (block-diag, 1 s-frag per chunk) + ReLU + CapsAct GEMM -> out
__global__ __launch_bounds__(256, 2) void caps_stage2(
    const f16* __restrict__ vt, const float* __restrict__ ws,
    const float* __restrict__ fb, const float* __restrict__ cab,
    float* __restrict__ out) {
  __shared__ float smemf[8704];  // 34.8 KB: vtile(26064B) / h1t(18432B) / outbuf aliased
  f16* vtile = (f16*)smemf;
  int bid = blockIdx.x;
  int b = bid >> 5, t5 = bid & 31;
  int ty = t5 >> 3, tx = t5 & 7;
  int tid = threadIdx.x;

  for (int i = tid; i < 181 * 8; i += 256) {
    int q2 = i & 7, hp = i >> 3;
    float4 val = make_float4(0.f, 0.f, 0.f, 0.f);
    if (hp < 180) {
      int hy = hp / 10, hx = hp - hy * 10;
      int gy = ty * 16 + hy - 1, gx = tx * 8 + hx - 1;
      if (gy >= 0 && gy < HH && gx >= 0 && gx < WW)
        val = ((const float4*)(vt + ((b * HH + gy) * WW + gx) * 64))[q2];
    }
    *(float4*)&vtile[hp * 72 + q2 * 8] = val;
  }
  __syncthreads();

  int w = __builtin_amdgcn_readfirstlane(tid >> 6);
  int lane = tid & 63;
  int q = lane >> 4, l15 = lane & 15;
  int h = l15 >> 3, j7 = l15 & 7;

  int hpt[2][3];
#pragma unroll
  for (int i2 = 0; i2 < 2; ++i2) {
    int pyA = (2 * w + i2) * 2 + h;
#pragma unroll
    for (int r = 0; r < 3; ++r) {
      int t = r * 4 + q;
      int hp = 180;
      if (t < 9) {
        int ky = t / 3, kx = t - ky * 3;
        hp = (pyA + ky) * 10 + j7 + kx;
      }
      hpt[i2][r] = hp * 72;
    }
  }

  const f16x8* bfv = (const f16x8*)((const f16*)(ws + 64) + BF_H);
  const f16x8* bcv = (const f16x8*)((const f16*)(ws + 64) + BC_H);

  // FeaExt: col (n=2s+h, j=j7); input chunk g feeds only s = g>>1
  f32x4 L[2][4];
#pragma unroll
  for (int s = 0; s < 4; ++s) {
    float bvv = fb[(2 * s + h) * 8 + j7];
    L[0][s] = (f32x4){bvv, bvv, bvv, bvv};
    L[1][s] = (f32x4){bvv, bvv, bvv, bvv};
  }
#pragma unroll
  for (int g = 0; g < 8; ++g) {
    int sg = g >> 1;
#pragma unroll
    for (int r = 0; r < 3; ++r) {
      f16x8 bf = bfv[(g * 3 + r) * 64 + lane];
#pragma unroll
      for (int i2 = 0; i2 < 2; ++i2) {
        f16x8 a = *(const f16x8*)&vtile[hpt[i2][r] + g * 8];
        L[i2][sg] = __builtin_amdgcn_mfma_f32_16x16x32_f16(a, bf, L[i2][sg], 0, 0, 0);
      }
    }
  }
#pragma unroll
  for (int i2 = 0; i2 < 2; ++i2)
#pragma unroll
    for (int s = 0; s < 4; ++s)
#pragma unroll
      for (int r = 0; r < 4; ++r) L[i2][s][r] = fmaxf(L[i2][s][r], 0.f);

  __syncthreads();  // vtile reads done; alias h1t
  f16* h1t = (f16*)smemf;  // [128][72], ch2 = n*8 + j1
#pragma unroll
  for (int i2 = 0; i2 < 2; ++i2)
#pragma unroll
    for (int s = 0; s < 4; ++s)
#pragma unroll
      for (int r = 0; r < 4; ++r)
        h1t[((2 * w + i2) * 16 + q * 4 + r) * 72 + (2 * s + h) * 8 + j7] =
            (f16)L[i2][s][r];
  __syncthreads();

  // CapsAct: K=64 over (j1, n) block-diag
  f32x4 H[2][4];
#pragma unroll
  for (int s = 0; s < 4; ++s) {
    float bvv = cab[(2 * s + h) * 8 + j7];
    H[0][s] = (f32x4){bvv, bvv, bvv, bvv};
    H[1][s] = (f32x4){bvv, bvv, bvv, bvv};
  }
#pragma unroll
  for (int c2 = 0; c2 < 2; ++c2) {
    f16x8 a2[2];
#pragma unroll
    for (int i2 = 0; i2 < 2; ++i2)
      a2[i2] = *(const f16x8*)&h1t[((2 * w + i2) * 16 + l15) * 72 + c2 * 32 + q * 8];
#pragma unroll
    for (int s = 0; s < 4; ++s) {
      f16x8 bc = bcv[(c2 * 4 + s) * 64 + lane];
#pragma unroll
      for (int i2 = 0; i2 < 2; ++i2)
        H[i2][s] = __builtin_amdgcn_mfma_f32_16x16x32_f16(a2[i2], bc, H[i2][s], 0, 0, 0);
    }
  }

  __syncthreads();  // h1t reads done; alias outbuf
  float* outbuf = smemf;  // [128][68], ch = j2*8 + n
#pragma unroll
  for (int i2 = 0; i2 < 2; ++i2)
#pragma unroll
    for (int s = 0; s < 4; ++s)
#pragma unroll
      for (int r = 0; r < 4; ++r)
        outbuf[((2 * w + i2) * 16 + q * 4 + r) * 68 + j7 * 8 + 2 * s + h] =
            H[i2][s][r];
  __syncthreads();

  for (int idx = tid; idx < 2048; idx += 256) {
    int p = idx >> 4, q4 = idx & 15;
    float4 val = *(float4*)&outbuf[p * 68 + q4 * 4];
    int gy = ty * 16 + (p >> 3), gx = tx * 8 + (p & 7);
    *(float4*)(out + ((b * HH + gy) * WW + gx) * 64 + q4 * 4) = val;
  }
}

extern "C" void kernel_launch(void* const* d_in, const int* in_sizes, int n_in,
                              void* d_out, int out_size, void* d_ws, size_t ws_size,
                              hipStream_t stream) {
  const float* inputs = (const float*)d_in[0];
  const float* attw   = (const float*)d_in[1];
  const float* ctw    = (const float*)d_in[2];
  const float* ctb    = (const float*)d_in[3];
  const float* few    = (const float*)d_in[4];
  const float* fb     = (const float*)d_in[5];
  const float* caw    = (const float*)d_in[6];
  const float* cab    = (const float*)d_in[7];
  float* out = (float*)d_out;
  float* ws  = (float*)d_ws;
  f16* vt = (f16*)(ws + 64) + VT_H;

  prep_kernel<<<(PREP_N + 255) / 256, 256, 0, stream>>>(attw, ctw, ctb, few, caw, ws);
  caps_stage1<<<32 * 32, 256, 0, stream>>>(inputs, ws, ctb, vt);
  caps_stage2<<<32 * 32, 256, 0, stream>>>(vt, ws, fb, cab, out);
}